// Round 1
// 1370.959 us; speedup vs baseline: 2.1629x; 2.1629x over previous
//
#include <hip/hip_runtime.h>

// Depthwise 3x3x3 conv (pad 1) -> InstanceNorm3d -> ReLU
// B=2, C=64, D=64, H=128, W=128, FP32.
//
// Round-2 rewrite: previous version was latency-bound (hbm 2.4% of peak,
// VALUBusy 11%) from a 9x global re-read per input with no LDS staging.
// New structure: each block owns (b, c, 16-row H tile, full W) across ALL d,
// marching depth with a ring-4 LDS slice buffer (18x128 f32 per slice, 36 KB).
// Per iteration: issue global loads for slice d+2 (regs), compute slice d from
// LDS, write prefetched slice to LDS, one __syncthreads (T14 issue-early /
// write-late). Each input element is fetched from HBM once per kernel
// (1.13x halo overfetch). W-halos via __shfl (stride-16B scalar LDS reads
// would be an 8-way bank conflict).

#define B_ 2
#define C_ 64
#define D_ 64
#define H_ 128
#define W_ 128

constexpr int HW  = H_ * W_;     // 16384
constexpr int DHW = D_ * HW;     // 1048576
constexpr float EPS_ = 1e-5f;
constexpr float INV_N = 1.0f / (float)DHW;

constexpr int TH = 16;                        // output rows per block
constexpr int LROWS = TH + 2;                 // 18 LDS rows per slice (h halo)
constexpr int SLICE_F4 = LROWS * W_ / 4;      // 576 float4 per slice

__global__ void k_zero(float* __restrict__ p, int n) {
    int i = blockIdx.x * 256 + threadIdx.x;
    if (i < n) p[i] = 0.f;
}

// MODE 0: accumulate sum / sum-of-squares of conv output into stats[2*bc..].
// MODE 1: recompute conv, normalize with stats, ReLU, store.
template<int MODE>
__global__ __launch_bounds__(256, 4) void k_fused(const float* __restrict__ x,
                                                  const float* __restrict__ wgt,
                                                  const float* __restrict__ gamma,
                                                  const float* __restrict__ beta,
                                                  float* __restrict__ stats,
                                                  float* __restrict__ out) {
    __shared__ float4 lds4[4 * SLICE_F4];     // 36,864 B ring of 4 slices
    __shared__ float red_s[4], red_ss[4];

    const int tid = threadIdx.x;
    const int h0  = blockIdx.x * TH;
    const int c   = blockIdx.y, b = blockIdx.z;
    const int bc  = b * C_ + c;
    const float* __restrict__ xc = x + (size_t)bc * DHW;

    float wf[27];
#pragma unroll
    for (int i = 0; i < 27; ++i) wf[i] = wgt[c * 27 + i];

    // thread -> 4 w x 2 adjacent rows. lanes 0..31 of a wave share a row pair.
    const int lr = (tid >> 5) << 1;           // 0,2,...,14 (local row pair)
    const int w0 = (tid & 31) << 2;           // 0..124

    // staging geometry (block-uniform). LDS row r holds global row h0-1+r.
    const int gh_lo = (h0 == 0) ? 0 : h0 - 1;
    const int gh_hi = (h0 + TH > H_ - 1) ? (H_ - 1) : (h0 + TH);
    const int n4    = (gh_hi - gh_lo + 1) * (W_ / 4);   // 544 or 576
    const int dst0  = (h0 == 0) ? (W_ / 4) : 0;         // skip LDS row 0 at top edge

    float scale = 0.f, shift = 0.f;
    if (MODE == 1) {
        float S = stats[2 * bc], SS = stats[2 * bc + 1];
        float mean = S * INV_N;
        float var  = SS * INV_N - mean * mean;
        float inv  = rsqrtf(var + EPS_);
        scale = gamma[c] * inv;
        shift = beta[c] - mean * scale;
    }

    // ---- prologue: stage slices 0 and 1 into ring slots 0,1 ----
    float4 pf[3];
    {
        float4 q0[3], q1[3];
        const float4* s0 = (const float4*)(xc + (size_t)gh_lo * W_);
        const float4* s1 = (const float4*)(xc + (size_t)HW + (size_t)gh_lo * W_);
#pragma unroll
        for (int k = 0; k < 3; ++k) {
            int i = tid + k * 256;
            if (i < n4) { q0[k] = s0[i]; q1[k] = s1[i]; }
        }
        float4* d0 = lds4 + 0 * SLICE_F4 + dst0;
        float4* d1 = lds4 + 1 * SLICE_F4 + dst0;
#pragma unroll
        for (int k = 0; k < 3; ++k) {
            int i = tid + k * 256;
            if (i < n4) { d0[i] = q0[k]; d1[i] = q1[k]; }
        }
    }
    __syncthreads();

    float s_sum = 0.f, s_sq = 0.f;

    for (int d = 0; d < D_; ++d) {
        // -- issue-early: global loads for slice d+2 (consumed next iters) --
        const int zp = d + 2;
        const bool do_pf = (zp < D_);
        if (do_pf) {
            const float4* src = (const float4*)(xc + (size_t)zp * HW + (size_t)gh_lo * W_);
#pragma unroll
            for (int k = 0; k < 3; ++k) {
                int i = tid + k * 256;
                if (i < n4) pf[k] = src[i];
            }
        }

        // -- compute slice d from LDS (slices d-1, d, d+1 resident) --
        float a0[4] = {0.f, 0.f, 0.f, 0.f};
        float a1[4] = {0.f, 0.f, 0.f, 0.f};
#pragma unroll
        for (int dd = 0; dd < 3; ++dd) {
            const int z = d + dd - 1;
            if ((unsigned)z >= (unsigned)D_) continue;          // zero-pad in d
            const float* bz = (const float*)(lds4 + (z & 3) * SLICE_F4);
#pragma unroll
            for (int rr = 0; rr < 4; ++rr) {
                const float* row = bz + (lr + rr) * W_;
                float4 m = *(const float4*)(row + w0);
                float lf = __shfl_up(m.w, 1);                   // w0-1 from lane-1
                float rg = __shfl_down(m.x, 1);                 // w0+4 from lane+1
                if (w0 == 0)          lf = 0.f;                 // zero-pad in w
                if (w0 + 4 >= W_)     rg = 0.f;
                if ((unsigned)(h0 + lr + rr - 1) >= (unsigned)H_) {  // zero-pad in h
                    m.x = m.y = m.z = m.w = 0.f; lf = 0.f; rg = 0.f;
                }
                if (rr < 3) {                                   // output row lr, dh=rr
                    const float* kk = wf + dd * 9 + rr * 3;
                    a0[0] = fmaf(lf,  kk[0], fmaf(m.x, kk[1], fmaf(m.y, kk[2], a0[0])));
                    a0[1] = fmaf(m.x, kk[0], fmaf(m.y, kk[1], fmaf(m.z, kk[2], a0[1])));
                    a0[2] = fmaf(m.y, kk[0], fmaf(m.z, kk[1], fmaf(m.w, kk[2], a0[2])));
                    a0[3] = fmaf(m.z, kk[0], fmaf(m.w, kk[1], fmaf(rg,  kk[2], a0[3])));
                }
                if (rr > 0) {                                   // output row lr+1, dh=rr-1
                    const float* kk = wf + dd * 9 + (rr - 1) * 3;
                    a1[0] = fmaf(lf,  kk[0], fmaf(m.x, kk[1], fmaf(m.y, kk[2], a1[0])));
                    a1[1] = fmaf(m.x, kk[0], fmaf(m.y, kk[1], fmaf(m.z, kk[2], a1[1])));
                    a1[2] = fmaf(m.y, kk[0], fmaf(m.z, kk[1], fmaf(m.w, kk[2], a1[2])));
                    a1[3] = fmaf(m.z, kk[0], fmaf(m.w, kk[1], fmaf(rg,  kk[2], a1[3])));
                }
            }
        }

        if (MODE == 0) {
            s_sum += a0[0] + a0[1] + a0[2] + a0[3] + a1[0] + a1[1] + a1[2] + a1[3];
            s_sq = fmaf(a0[0], a0[0], s_sq); s_sq = fmaf(a0[1], a0[1], s_sq);
            s_sq = fmaf(a0[2], a0[2], s_sq); s_sq = fmaf(a0[3], a0[3], s_sq);
            s_sq = fmaf(a1[0], a1[0], s_sq); s_sq = fmaf(a1[1], a1[1], s_sq);
            s_sq = fmaf(a1[2], a1[2], s_sq); s_sq = fmaf(a1[3], a1[3], s_sq);
        } else {
            float* ob = out + (size_t)bc * DHW + (size_t)d * HW
                            + (size_t)(h0 + lr) * W_ + w0;
            float4 o0, o1;
            o0.x = fmaxf(fmaf(a0[0], scale, shift), 0.f);
            o0.y = fmaxf(fmaf(a0[1], scale, shift), 0.f);
            o0.z = fmaxf(fmaf(a0[2], scale, shift), 0.f);
            o0.w = fmaxf(fmaf(a0[3], scale, shift), 0.f);
            o1.x = fmaxf(fmaf(a1[0], scale, shift), 0.f);
            o1.y = fmaxf(fmaf(a1[1], scale, shift), 0.f);
            o1.z = fmaxf(fmaf(a1[2], scale, shift), 0.f);
            o1.w = fmaxf(fmaf(a1[3], scale, shift), 0.f);
            *(float4*)ob        = o0;
            *(float4*)(ob + W_) = o1;
        }

        // -- write-late: deposit prefetched slice into ring slot (d+2)&3 --
        // (that slot holds slice d-2, which no one reads this iteration)
        if (do_pf) {
            float4* dst = lds4 + (zp & 3) * SLICE_F4 + dst0;
#pragma unroll
            for (int k = 0; k < 3; ++k) {
                int i = tid + k * 256;
                if (i < n4) dst[i] = pf[k];
            }
        }
        __syncthreads();
    }

    if (MODE == 0) {
#pragma unroll
        for (int off = 32; off; off >>= 1) {
            s_sum += __shfl_down(s_sum, off);
            s_sq  += __shfl_down(s_sq,  off);
        }
        int wave = tid >> 6;
        if ((tid & 63) == 0) { red_s[wave] = s_sum; red_ss[wave] = s_sq; }
        __syncthreads();
        if (tid == 0) {
            atomicAdd(&stats[2 * bc],     red_s[0] + red_s[1] + red_s[2] + red_s[3]);
            atomicAdd(&stats[2 * bc + 1], red_ss[0] + red_ss[1] + red_ss[2] + red_ss[3]);
        }
    }
}

extern "C" void kernel_launch(void* const* d_in, const int* in_sizes, int n_in,
                              void* d_out, int out_size, void* d_ws, size_t ws_size,
                              hipStream_t stream) {
    const float* x     = (const float*)d_in[0];
    const float* wgt   = (const float*)d_in[1];
    const float* gamma = (const float*)d_in[2];
    const float* beta  = (const float*)d_in[3];
    float* out   = (float*)d_out;
    float* stats = (float*)d_ws;   // 2 * B * C floats = 1 KiB

    k_zero<<<dim3(1), dim3(256), 0, stream>>>(stats, 2 * B_ * C_);

    dim3 grid(H_ / TH, C_, B_);    // 8, 64, 2 = 1024 blocks (4 per CU, LDS-capped)
    dim3 block(256);
    k_fused<0><<<grid, block, 0, stream>>>(x, wgt, gamma, beta, stats, out);
    k_fused<1><<<grid, block, 0, stream>>>(x, wgt, gamma, beta, stats, out);
}